// Round 1
// baseline (611.530 us; speedup 1.0000x reference)
//
#include <hip/hip_runtime.h>

#define N_NODES 24
#define CH 32
#define SPB 64        // samples per block
#define NPQ 6         // nodes per quarter (grid.y = 4 quarters)
#define THREADS 384   // 6 waves: one wave per node of the quarter

// Phase 1: block-cooperative coalesced load of a [64 sample][6 node] h slice
//          (768B contiguous runs -> ~16 lines/instr vs 64 for the old per-lane
//          3072B-stride gather) + one coalesced read of each sample's valid row.
// Phase 2: wave w computes node 6q+w for 64 samples (lane = sample); weights
//          remain wave-uniform (readfirstlane) -> SGPR s_loads, VALU does FMAs.
// Phase 3: staged outputs written back chunked (24B/sample runs).
__global__ __launch_bounds__(THREADS) void grouped_pnmlp_kernel(
    const float* __restrict__ h,      // [B][24][32]
    const int*   __restrict__ valid,  // [B][24]
    const float* __restrict__ W1,     // [6][4][32][32]
    const float* __restrict__ b1,     // [6][4][32]
    const float* __restrict__ W2,     // [6][4][32]
    const float* __restrict__ b2,     // [6][4]
    float*       __restrict__ out,    // [B][24]
    int n_samples)
{
    __shared__ float xs[SPB][196];   // relu'd h tile: [sample][6*32 floats + 4 pad]
    __shared__ float gs[SPB][6];     // per-sample group-valid bits
    __shared__ float os[SPB][NPQ];   // staged outputs

    const int t  = threadIdx.x;
    const int q  = blockIdx.y;              // nodes 6q .. 6q+5
    const int s0 = blockIdx.x * SPB;

    // ---- phase 1a: coalesced h slice load (+relu) into LDS
    // sample row = 192 float4; this quarter = float4 [q*48, q*48+48)
    const float4* __restrict__ hv = (const float4*)h;
    float4 r[8];
#pragma unroll
    for (int i = 0; i < 8; ++i) {
        const int f = i * THREADS + t;      // 0..3071
        const int s = f / 48, c = f % 48;
        int sg = s0 + s; if (sg >= n_samples) sg = n_samples - 1;
        r[i] = hv[(size_t)sg * 192 + q * 48 + c];
    }
#pragma unroll
    for (int i = 0; i < 8; ++i) {
        const int f = i * THREADS + t;
        const int s = f / 48, c = f % 48;
        float4 v = r[i];
        v.x = fmaxf(v.x, 0.0f); v.y = fmaxf(v.y, 0.0f);
        v.z = fmaxf(v.z, 0.0f); v.w = fmaxf(v.w, 0.0f);
        *(float4*)&xs[s][4 * c] = v;
    }

    // ---- phase 1b: group validity bits, one lane per sample (wave 0 only)
    if (t < SPB) {
        int sg = s0 + t; if (sg >= n_samples) sg = n_samples - 1;
        const int4* __restrict__ vp = (const int4*)(valid + (size_t)sg * N_NODES);
        const int4 a = vp[0], b = vp[1], c = vp[2], d = vp[3], e = vp[4], f = vp[5];
        gs[t][0] = (a.x + a.w + b.z + c.y > 0) ? 1.0f : 0.0f;  // 0,3,6,9
        gs[t][1] = (a.y + b.x + b.w + c.z > 0) ? 1.0f : 0.0f;  // 1,4,7,10
        gs[t][2] = (a.z + b.y + c.x + c.w > 0) ? 1.0f : 0.0f;  // 2,5,8,11
        gs[t][3] = (d.x + d.y + d.z + d.w > 0) ? 1.0f : 0.0f;  // 12..15
        gs[t][4] = (e.x + e.z + f.x + f.z > 0) ? 1.0f : 0.0f;  // 16,18,20,22
        gs[t][5] = (e.y + e.w + f.y + f.w > 0) ? 1.0f : 0.0f;  // 17,19,21,23
    }
    __syncthreads();

    // ---- phase 2: wave = node, lane = sample
    const int w    = __builtin_amdgcn_readfirstlane(t >> 6);  // force SGPR
    const int lane = t & 63;
    const int node = q * NPQ + w;

    int g, k;
    if (node < 12)      { g = node % 3;               k = node / 3;        }
    else if (node < 16) { g = 3;                      k = node - 12;       }
    else                { g = 4 + ((node - 16) & 1);  k = (node - 16) >> 1; }

    const int gk = g * 4 + k;
    const float* __restrict__ w1  = W1 + (size_t)gk * CH * CH;  // [l][j]
    const float* __restrict__ w2  = W2 + (size_t)gk * CH;
    const float* __restrict__ bb1 = b1 + (size_t)gk * CH;
    const float               bb2 = b2[gk];

    float x[CH];
#pragma unroll
    for (int i = 0; i < 8; ++i) {
        const float4 v = *(const float4*)&xs[lane][w * CH + 4 * i];
        x[4*i+0] = v.x; x[4*i+1] = v.y; x[4*i+2] = v.z; x[4*i+3] = v.w;
    }

    float hid[CH];
#pragma unroll
    for (int j = 0; j < CH; ++j) hid[j] = bb1[j];
#pragma unroll
    for (int l = 0; l < CH; ++l) {
        const float xl = x[l];
#pragma unroll
        for (int j = 0; j < CH; ++j)
            hid[j] = fmaf(xl, w1[l * CH + j], hid[j]);
    }

    float acc = bb2;
#pragma unroll
    for (int j = 0; j < CH; ++j)
        acc = fmaf(fmaxf(hid[j], 0.0f), w2[j], acc);

    os[lane][w] = acc * gs[lane][g];
    __syncthreads();

    // ---- phase 3: chunked store (6 floats = 24B per sample)
    {
        const int s = t / 6, j = t % 6;
        const int sg = s0 + s;
        if (sg < n_samples)
            out[(size_t)sg * N_NODES + q * NPQ + j] = os[s][j];
    }
}

extern "C" void kernel_launch(void* const* d_in, const int* in_sizes, int n_in,
                              void* d_out, int out_size, void* d_ws, size_t ws_size,
                              hipStream_t stream) {
    const float* h     = (const float*)d_in[0];
    const int*   valid = (const int*)d_in[1];
    const float* W1    = (const float*)d_in[2];
    const float* b1    = (const float*)d_in[3];
    const float* W2    = (const float*)d_in[4];
    const float* b2    = (const float*)d_in[5];
    float* out = (float*)d_out;

    const int n_samples = in_sizes[0] / (N_NODES * CH);

    dim3 block(THREADS, 1, 1);
    dim3 grid((n_samples + SPB - 1) / SPB, 4, 1);
    grouped_pnmlp_kernel<<<grid, block, 0, stream>>>(h, valid, W1, b1, W2, b2,
                                                     out, n_samples);
}

// Round 2
// 589.866 us; speedup vs baseline: 1.0367x; 1.0367x over previous
//
#include <hip/hip_runtime.h>

#define N_NODES 24
#define CH 32
#define SPW 64          // samples per block (one per lane)
#define WAVES 4
#define THREADS 256
#define NPW 6           // nodes per wave: node = w + 4*ni

// Barrier-free persistent form. Wave w of each block computes nodes
// {w, w+4, ..., w+20} for 64 samples (lane = sample). h fragment for node
// n+1 is prefetched into registers while node n's 1024-FMA loop runs.
// Weights stay wave-uniform -> SGPR s_loads; valid row read once per lane.
__global__ __launch_bounds__(THREADS) void grouped_pnmlp_kernel(
    const float* __restrict__ h,      // [B][24][32]
    const int*   __restrict__ valid,  // [B][24]
    const float* __restrict__ W1,     // [6][4][32][32]
    const float* __restrict__ b1,     // [6][4][32]
    const float* __restrict__ W2,     // [6][4][32]
    const float* __restrict__ b2,     // [6][4]
    float*       __restrict__ out,    // [B][24]
    int n_samples)
{
    const int w    = __builtin_amdgcn_readfirstlane(threadIdx.x >> 6);
    const int lane = threadIdx.x & 63;

    int s = blockIdx.x * SPW + lane;
    const bool live = (s < n_samples);
    if (!live) s = n_samples - 1;           // clamp loads, mask stores

    // ---- per-lane validity: one coalesced-ish 96B read, 6 group bits in regs
    const int4* __restrict__ vp = (const int4*)(valid + (size_t)s * N_NODES);
    const int4 a = vp[0], b = vp[1], c = vp[2], d = vp[3], e = vp[4], f = vp[5];
    const float gv0 = (a.x + a.w + b.z + c.y > 0) ? 1.0f : 0.0f;  // 0,3,6,9
    const float gv1 = (a.y + b.x + b.w + c.z > 0) ? 1.0f : 0.0f;  // 1,4,7,10
    const float gv2 = (a.z + b.y + c.x + c.w > 0) ? 1.0f : 0.0f;  // 2,5,8,11
    const float gv3 = (d.x + d.y + d.z + d.w > 0) ? 1.0f : 0.0f;  // 12..15
    const float gv4 = (e.x + e.z + f.x + f.z > 0) ? 1.0f : 0.0f;  // 16,18,20,22
    const float gv5 = (e.y + e.w + f.y + f.w > 0) ? 1.0f : 0.0f;  // 17,19,21,23

    const float4* __restrict__ hrow = (const float4*)(h + (size_t)s * N_NODES * CH);

    float4 cur[8], nxt[8];
#pragma unroll
    for (int i = 0; i < 8; ++i) cur[i] = hrow[w * 8 + i];

#pragma unroll
    for (int ni = 0; ni < NPW; ++ni) {
        const int node = w + 4 * ni;        // wave-uniform

        // prefetch next node's h fragment (hidden under the FMA loop)
        if (ni + 1 < NPW) {
#pragma unroll
            for (int i = 0; i < 8; ++i) nxt[i] = hrow[(node + 4) * 8 + i];
        }

        int g, k;
        if (node < 12)      { g = node % 3;               k = node / 3;        }
        else if (node < 16) { g = 3;                      k = node - 12;       }
        else                { g = 4 + ((node - 16) & 1);  k = (node - 16) >> 1; }
        const int gk = g * 4 + k;

        const float* __restrict__ w1  = W1 + (size_t)gk * CH * CH;  // [l][j]
        const float* __restrict__ w2  = W2 + (size_t)gk * CH;
        const float* __restrict__ bb1 = b1 + (size_t)gk * CH;
        const float               bb2 = b2[gk];

        float x[CH];
#pragma unroll
        for (int i = 0; i < 8; ++i) {
            x[4*i+0] = fmaxf(cur[i].x, 0.0f);
            x[4*i+1] = fmaxf(cur[i].y, 0.0f);
            x[4*i+2] = fmaxf(cur[i].z, 0.0f);
            x[4*i+3] = fmaxf(cur[i].w, 0.0f);
        }

        float hid[CH];
#pragma unroll
        for (int j = 0; j < CH; ++j) hid[j] = bb1[j];
#pragma unroll
        for (int l = 0; l < CH; ++l) {
            const float xl = x[l];
#pragma unroll
            for (int j = 0; j < CH; ++j)
                hid[j] = fmaf(xl, w1[l * CH + j], hid[j]);
        }

        float acc = bb2;
#pragma unroll
        for (int j = 0; j < CH; ++j)
            acc = fmaf(fmaxf(hid[j], 0.0f), w2[j], acc);

        // named-scalar select (no runtime-indexed reg array -> no scratch)
        const float gvsel = (g == 0) ? gv0 : (g == 1) ? gv1 : (g == 2) ? gv2
                          : (g == 3) ? gv3 : (g == 4) ? gv4 : gv5;

        if (live) out[(size_t)s * N_NODES + node] = acc * gvsel;

        if (ni + 1 < NPW) {
#pragma unroll
            for (int i = 0; i < 8; ++i) cur[i] = nxt[i];
        }
    }
}

extern "C" void kernel_launch(void* const* d_in, const int* in_sizes, int n_in,
                              void* d_out, int out_size, void* d_ws, size_t ws_size,
                              hipStream_t stream) {
    const float* h     = (const float*)d_in[0];
    const int*   valid = (const int*)d_in[1];
    const float* W1    = (const float*)d_in[2];
    const float* b1    = (const float*)d_in[3];
    const float* W2    = (const float*)d_in[4];
    const float* b2    = (const float*)d_in[5];
    float* out = (float*)d_out;

    const int n_samples = in_sizes[0] / (N_NODES * CH);

    dim3 block(THREADS, 1, 1);
    dim3 grid((n_samples + SPW - 1) / SPW, 1, 1);
    grouped_pnmlp_kernel<<<grid, block, 0, stream>>>(h, valid, W1, b1, W2, b2,
                                                     out, n_samples);
}

// Round 3
// 585.330 us; speedup vs baseline: 1.0448x; 1.0078x over previous
//
#include <hip/hip_runtime.h>

#define N_NODES 24
#define CH 32
#define SPW 64          // samples per block (one per lane)
#define THREADS 256
#define NPW 6           // nodes per wave: node = w + 4*ni

// Barrier-free persistent form, v2: software pipeline rotates through x.
//   x = relu(cur)  -> cur is dead -> re-issue next node's 8 loads into cur
//   -> 1024-FMA loop on x hides the load latency.
// No nxt[] array, no v_mov copies: ~115 VGPRs -> __launch_bounds__(,4)
// gives 4 waves/SIMD (vs 3) for +33% in-flight latency hiding.
// Weights stay wave-uniform (readfirstlane'd node) -> SGPR s_loads.
__global__ __launch_bounds__(THREADS, 4) void grouped_pnmlp_kernel(
    const float* __restrict__ h,      // [B][24][32]
    const int*   __restrict__ valid,  // [B][24]
    const float* __restrict__ W1,     // [6][4][32][32]
    const float* __restrict__ b1,     // [6][4][32]
    const float* __restrict__ W2,     // [6][4][32]
    const float* __restrict__ b2,     // [6][4]
    float*       __restrict__ out,    // [B][24]
    int n_samples)
{
    const int w    = __builtin_amdgcn_readfirstlane(threadIdx.x >> 6);
    const int lane = threadIdx.x & 63;

    int s = blockIdx.x * SPW + lane;
    const bool live = (s < n_samples);
    if (!live) s = n_samples - 1;           // clamp loads, mask stores

    const float4* __restrict__ hrow = (const float4*)(h + (size_t)s * N_NODES * CH);

    // first node's fragment — issued before the valid loads so the first
    // x-extraction waits at vmcnt(6), not vmcnt(0)
    float4 cur[8];
#pragma unroll
    for (int i = 0; i < 8; ++i) cur[i] = hrow[w * 8 + i];

    // ---- per-lane validity: 96B read once, 6 group bits in regs
    const int4* __restrict__ vp = (const int4*)(valid + (size_t)s * N_NODES);
    const int4 a = vp[0], b = vp[1], c = vp[2], d = vp[3], e = vp[4], f = vp[5];
    const float gv0 = (a.x + a.w + b.z + c.y > 0) ? 1.0f : 0.0f;  // 0,3,6,9
    const float gv1 = (a.y + b.x + b.w + c.z > 0) ? 1.0f : 0.0f;  // 1,4,7,10
    const float gv2 = (a.z + b.y + c.x + c.w > 0) ? 1.0f : 0.0f;  // 2,5,8,11
    const float gv3 = (d.x + d.y + d.z + d.w > 0) ? 1.0f : 0.0f;  // 12..15
    const float gv4 = (e.x + e.z + f.x + f.z > 0) ? 1.0f : 0.0f;  // 16,18,20,22
    const float gv5 = (e.y + e.w + f.y + f.w > 0) ? 1.0f : 0.0f;  // 17,19,21,23

#pragma unroll
    for (int ni = 0; ni < NPW; ++ni) {
        const int node = w + 4 * ni;        // wave-uniform

        // consume cur into x (relu) — cur becomes dead here
        float x[CH];
#pragma unroll
        for (int i = 0; i < 8; ++i) {
            x[4*i+0] = fmaxf(cur[i].x, 0.0f);
            x[4*i+1] = fmaxf(cur[i].y, 0.0f);
            x[4*i+2] = fmaxf(cur[i].z, 0.0f);
            x[4*i+3] = fmaxf(cur[i].w, 0.0f);
        }

        // refill cur with node n+1's fragment; latency hidden by FMA loop
        if (ni + 1 < NPW) {
#pragma unroll
            for (int i = 0; i < 8; ++i) cur[i] = hrow[(node + 4) * 8 + i];
        }

        int g, k;
        if (node < 12)      { g = node % 3;               k = node / 3;        }
        else if (node < 16) { g = 3;                      k = node - 12;       }
        else                { g = 4 + ((node - 16) & 1);  k = (node - 16) >> 1; }
        const int gk = g * 4 + k;

        const float* __restrict__ w1  = W1 + (size_t)gk * CH * CH;  // [l][j]
        const float* __restrict__ w2  = W2 + (size_t)gk * CH;
        const float* __restrict__ bb1 = b1 + (size_t)gk * CH;
        const float               bb2 = b2[gk];

        float hid[CH];
#pragma unroll
        for (int j = 0; j < CH; ++j) hid[j] = bb1[j];
#pragma unroll
        for (int l = 0; l < CH; ++l) {
            const float xl = x[l];
#pragma unroll
            for (int j = 0; j < CH; ++j)
                hid[j] = fmaf(xl, w1[l * CH + j], hid[j]);
        }

        float acc = bb2;
#pragma unroll
        for (int j = 0; j < CH; ++j)
            acc = fmaf(fmaxf(hid[j], 0.0f), w2[j], acc);

        // named-scalar select (no runtime-indexed reg array -> no scratch)
        const float gvsel = (g == 0) ? gv0 : (g == 1) ? gv1 : (g == 2) ? gv2
                          : (g == 3) ? gv3 : (g == 4) ? gv4 : gv5;

        if (live) out[(size_t)s * N_NODES + node] = acc * gvsel;
    }
}

extern "C" void kernel_launch(void* const* d_in, const int* in_sizes, int n_in,
                              void* d_out, int out_size, void* d_ws, size_t ws_size,
                              hipStream_t stream) {
    const float* h     = (const float*)d_in[0];
    const int*   valid = (const int*)d_in[1];
    const float* W1    = (const float*)d_in[2];
    const float* b1    = (const float*)d_in[3];
    const float* W2    = (const float*)d_in[4];
    const float* b2    = (const float*)d_in[5];
    float* out = (float*)d_out;

    const int n_samples = in_sizes[0] / (N_NODES * CH);

    dim3 block(THREADS, 1, 1);
    dim3 grid((n_samples + SPW - 1) / SPW, 1, 1);
    grouped_pnmlp_kernel<<<grid, block, 0, stream>>>(h, valid, W1, b1, W2, b2,
                                                     out, n_samples);
}